// Round 1
// baseline (448.479 us; speedup 1.0000x reference)
//
#include <hip/hip_runtime.h>
#include <hip/hip_bf16.h>
#include <stdint.h>
#include <stddef.h>

typedef __bf16 bf16_t;
typedef __bf16 bf16x4_t __attribute__((ext_vector_type(4)));
typedef __bf16 bf16x8_t __attribute__((ext_vector_type(8)));
typedef float f32x4 __attribute__((ext_vector_type(4)));

#define D_MODEL 2048
#define NHEADS 16
#define HDIM 128
#define SEQ 2048
#define BATCH 2
#define MTOT (BATCH * SEQ) /* 4096 */
#define SCALE_F 0.08838834764831845f /* 1/sqrt(128) */

#define AS1 __attribute__((address_space(1)))
#define AS3 __attribute__((address_space(3)))

__device__ __forceinline__ void load_lds16(const bf16_t* g, bf16_t* l) {
  __builtin_amdgcn_global_load_lds((AS1 void*)(g), (AS3 void*)(l), 16, 0, 0);
}

// ---------------------------------------------------------------- cast fp32->bf16
__global__ void cast_kernel(const float* __restrict__ src, bf16_t* __restrict__ dst, int n4) {
  int i = blockIdx.x * blockDim.x + threadIdx.x;
  if (i < n4) {
    float4 v = ((const float4*)src)[i];
    bf16x4_t o;
    o.x = (bf16_t)v.x; o.y = (bf16_t)v.y; o.z = (bf16_t)v.z; o.w = (bf16_t)v.w;
    ((bf16x4_t*)dst)[i] = o;
  }
}

// ---------------------------------------------------------------- GEMM  C = A @ B^T (+bias)
// A: [4096][2048] bf16 row-major.  Bm: [N][2048] bf16 row-major (N x K = B^T layout).
// mode 0: N=6144 (q|k|v). Epilogue -> Q,K as [B,H,S,Dh]; V transposed -> [B,H,Dh,S].
// mode 1: N=2048. Epilogue -> fp32 out [4096][2048] + bias.
__global__ __launch_bounds__(256) void gemm_fused(
    const bf16_t* __restrict__ A, const bf16_t* __restrict__ Bm, int mode,
    const float* __restrict__ bias0, const float* __restrict__ bias1,
    const float* __restrict__ bias2,
    bf16_t* __restrict__ Qo, bf16_t* __restrict__ Ko, bf16_t* __restrict__ Vto,
    float* __restrict__ Out) {
  const int K = 2048;
  __shared__ __align__(16) bf16_t lA[128 * 32];
  __shared__ __align__(16) bf16_t lB[128 * 32];
  const int m0 = blockIdx.x * 128;
  const int n0 = blockIdx.y * 128;
  const int t = threadIdx.x;
  const int w = t >> 6, lane = t & 63;
  const int wm = w & 1, wn = w >> 1;
  const int la = lane & 15, lb = lane >> 4;

  f32x4 acc[4][4];
  f32x4 zero = {0.f, 0.f, 0.f, 0.f};
#pragma unroll
  for (int i = 0; i < 4; i++)
#pragma unroll
    for (int j = 0; j < 4; j++) acc[i][j] = zero;

  const bf16_t* gA0 = A + (size_t)(m0 + (t >> 2)) * K + (t & 3) * 8;
  const bf16_t* gA1 = gA0 + (size_t)64 * K;
  const bf16_t* gB0 = Bm + (size_t)(n0 + (t >> 2)) * K + (t & 3) * 8;
  const bf16_t* gB1 = gB0 + (size_t)64 * K;
  bf16_t* sA = lA + t * 8;
  bf16_t* sB = lB + t * 8;

  for (int k0 = 0; k0 < K; k0 += 32) {
    __syncthreads();
    load_lds16(gA0 + k0, sA);
    load_lds16(gA1 + k0, sA + 2048);
    load_lds16(gB0 + k0, sB);
    load_lds16(gB1 + k0, sB + 2048);
    __syncthreads();
    bf16x8_t af[4], bfr[4];
#pragma unroll
    for (int mt = 0; mt < 4; mt++)
      af[mt] = *(const bf16x8_t*)(lA + (wm * 64 + mt * 16 + la) * 32 + lb * 8);
#pragma unroll
    for (int nt = 0; nt < 4; nt++)
      bfr[nt] = *(const bf16x8_t*)(lB + (wn * 64 + nt * 16 + la) * 32 + lb * 8);
#pragma unroll
    for (int mt = 0; mt < 4; mt++)
#pragma unroll
      for (int nt = 0; nt < 4; nt++)
        acc[mt][nt] = __builtin_amdgcn_mfma_f32_16x16x32_bf16(af[mt], bfr[nt], acc[mt][nt], 0, 0, 0);
  }

  if (mode == 0) {
#pragma unroll
    for (int mt = 0; mt < 4; mt++) {
#pragma unroll
      for (int nt = 0; nt < 4; nt++) {
        int m = m0 + wm * 64 + mt * 16 + lb * 4; // rows m..m+3
        int n = n0 + wn * 64 + nt * 16 + la;
        int b = m >> 11, s = m & 2047;
        int which = n >> 11, hd = n & 2047;
        int h = hd >> 7, d = hd & 127;
        float bv = (which == 0 ? bias0 : which == 1 ? bias1 : bias2)[hd];
        f32x4 v = acc[mt][nt];
        if (which == 2) {
          bf16_t* dst = Vto + ((size_t)(b * NHEADS + h) * HDIM + d) * SEQ + s;
          bf16x4_t pk;
          pk.x = (bf16_t)(v.x + bv); pk.y = (bf16_t)(v.y + bv);
          pk.z = (bf16_t)(v.z + bv); pk.w = (bf16_t)(v.w + bv);
          *(bf16x4_t*)dst = pk;
        } else {
          bf16_t* dst = (which == 0 ? Qo : Ko) + ((size_t)(b * NHEADS + h) * SEQ + s) * HDIM + d;
          dst[0]        = (bf16_t)(v.x + bv);
          dst[HDIM]     = (bf16_t)(v.y + bv);
          dst[2 * HDIM] = (bf16_t)(v.z + bv);
          dst[3 * HDIM] = (bf16_t)(v.w + bv);
        }
      }
    }
  } else {
#pragma unroll
    for (int mt = 0; mt < 4; mt++) {
#pragma unroll
      for (int nt = 0; nt < 4; nt++) {
        int m = m0 + wm * 64 + mt * 16 + lb * 4;
        int n = n0 + wn * 64 + nt * 16 + la;
        float bv = bias0[n];
        f32x4 v = acc[mt][nt];
        float* dst = Out + (size_t)m * D_MODEL + n;
        dst[0]           = v.x + bv;
        dst[D_MODEL]     = v.y + bv;
        dst[2 * D_MODEL] = v.z + bv;
        dst[3 * D_MODEL] = v.w + bv;
      }
    }
  }
}

// ---------------------------------------------------------------- causal flash attention
// Q,K: [32][2048][128] bf16.  Vt: [32][128][2048] bf16.  O: [2][2048][2048] bf16.
__global__ __launch_bounds__(256) void flash_attn(
    const bf16_t* __restrict__ Q, const bf16_t* __restrict__ Kg,
    const bf16_t* __restrict__ Vt, bf16_t* __restrict__ O) {
  __shared__ __align__(16) bf16_t lK[64 * 128];  // [j][d], chunk-swizzled
  __shared__ __align__(16) bf16_t lV[128 * 64];  // [d][j], chunk-swizzled
  __shared__ __align__(16) bf16_t lP[128 * 72];  // [q][j], padded stride 72
  int g = blockIdx.x;
  int qt, bh;
  if (g < 256) { qt = g >> 5; bh = g & 31; }
  else         { qt = 15 - ((g - 256) >> 5); bh = g & 31; }
  const int q0 = qt * 128;
  const int t = threadIdx.x;
  const int w = t >> 6, lane = t & 63;
  const int la = lane & 15, lb = lane >> 4;

  const bf16_t* Qb = Q + (size_t)bh * SEQ * HDIM;
  const bf16_t* Kb = Kg + (size_t)bh * SEQ * HDIM;
  const bf16_t* Vb = Vt + (size_t)bh * HDIM * SEQ;

  // Q fragments in registers: rows q0+32w+16mt+la, k = 32ks + 8lb + i
  bf16x8_t qf[2][4];
#pragma unroll
  for (int mt = 0; mt < 2; mt++)
#pragma unroll
    for (int ks = 0; ks < 4; ks++)
      qf[mt][ks] = *(const bf16x8_t*)(Qb + (size_t)(q0 + w * 32 + mt * 16 + la) * HDIM + ks * 32 + lb * 8);

  f32x4 oacc[2][8];
  float mrow[2][4], lrow[2][4];
  f32x4 zero = {0.f, 0.f, 0.f, 0.f};
#pragma unroll
  for (int mt = 0; mt < 2; mt++) {
#pragma unroll
    for (int dt = 0; dt < 8; dt++) oacc[mt][dt] = zero;
#pragma unroll
    for (int r = 0; r < 4; r++) { mrow[mt][r] = -3.0e38f; lrow[mt][r] = 0.f; }
  }

  const int nkt = qt * 2 + 2;
  for (int kt = 0; kt < nkt; kt++) {
    const int j0 = kt * 64;
    __syncthreads();
    // stage K-tile [64][128]: chunk (j, cc') holds global chunk (j, cc'^ (j&15))
#pragma unroll
    for (int i = 0; i < 4; i++) {
      int slot = t + 256 * i;
      int j = slot >> 4, cc = slot & 15;
      load_lds16(Kb + (size_t)(j0 + j) * HDIM + ((cc ^ (j & 15)) * 8), lK + slot * 8);
    }
    // stage Vt-tile [128][64]: chunk (d, jc') holds global chunk (d, jc'^(d&7))
#pragma unroll
    for (int i = 0; i < 4; i++) {
      int slot = t + 256 * i;
      int d = slot >> 3, jc = slot & 7;
      load_lds16(Vb + (size_t)d * SEQ + j0 + ((jc ^ (d & 7)) * 8), lV + slot * 8);
    }
    __syncthreads();

    // S = Q @ K^T   (rows: this wave's 32 q's; cols: 64 j's)
    f32x4 sacc[2][4];
#pragma unroll
    for (int mt = 0; mt < 2; mt++)
#pragma unroll
      for (int nt = 0; nt < 4; nt++) sacc[mt][nt] = zero;
#pragma unroll
    for (int ks = 0; ks < 4; ks++) {
#pragma unroll
      for (int nt = 0; nt < 4; nt++) {
        int j = nt * 16 + la;
        int cc = (lb + 4 * ks) ^ (j & 15);
        bf16x8_t kf = *(const bf16x8_t*)(lK + j * 128 + cc * 8);
#pragma unroll
        for (int mt = 0; mt < 2; mt++)
          sacc[mt][nt] = __builtin_amdgcn_mfma_f32_16x16x32_bf16(qf[mt][ks], kf, sacc[mt][nt], 0, 0, 0);
      }
    }

    // scale + causal mask + online softmax
#pragma unroll
    for (int mt = 0; mt < 2; mt++) {
      int qrow = q0 + w * 32 + mt * 16 + lb * 4;
      f32x4 rmax;
#pragma unroll
      for (int r = 0; r < 4; r++) {
        float x = -3.0e38f;
#pragma unroll
        for (int nt = 0; nt < 4; nt++) {
          int j = j0 + nt * 16 + la;
          float sv = sacc[mt][nt][r] * SCALE_F;
          if (j > qrow + r) sv = -3.0e38f;
          sacc[mt][nt][r] = sv;
          x = fmaxf(x, sv);
        }
        rmax[r] = x;
      }
#pragma unroll
      for (int off = 1; off < 16; off <<= 1)
#pragma unroll
        for (int r = 0; r < 4; r++) rmax[r] = fmaxf(rmax[r], __shfl_xor(rmax[r], off));
      f32x4 rsum;
#pragma unroll
      for (int r = 0; r < 4; r++) {
        float mnew = fmaxf(mrow[mt][r], rmax[r]);
        float alpha = __expf(mrow[mt][r] - mnew);
        mrow[mt][r] = mnew;
        lrow[mt][r] *= alpha;
#pragma unroll
        for (int dt = 0; dt < 8; dt++) oacc[mt][dt][r] *= alpha;
        float s = 0.f;
#pragma unroll
        for (int nt = 0; nt < 4; nt++) {
          float pex = __expf(sacc[mt][nt][r] - mnew);
          sacc[mt][nt][r] = pex;
          s += pex;
        }
        rsum[r] = s;
      }
#pragma unroll
      for (int off = 1; off < 16; off <<= 1)
#pragma unroll
        for (int r = 0; r < 4; r++) rsum[r] += __shfl_xor(rsum[r], off);
#pragma unroll
      for (int r = 0; r < 4; r++) lrow[mt][r] += rsum[r];
      // write P (this wave's own 32 rows only -> no cross-wave barrier needed)
#pragma unroll
      for (int nt = 0; nt < 4; nt++)
#pragma unroll
        for (int r = 0; r < 4; r++)
          lP[(w * 32 + mt * 16 + lb * 4 + r) * 72 + nt * 16 + la] = (bf16_t)sacc[mt][nt][r];
    }

    // O += P @ V
    bf16x8_t pf[2][2];
#pragma unroll
    for (int mt = 0; mt < 2; mt++)
#pragma unroll
      for (int ks = 0; ks < 2; ks++)
        pf[mt][ks] = *(const bf16x8_t*)(lP + (w * 32 + mt * 16 + la) * 72 + ks * 32 + lb * 8);
#pragma unroll
    for (int ks = 0; ks < 2; ks++) {
#pragma unroll
      for (int dt = 0; dt < 8; dt++) {
        int d = dt * 16 + la;
        int jc = (lb + 4 * ks) ^ (d & 7);
        bf16x8_t vf = *(const bf16x8_t*)(lV + d * 64 + jc * 8);
#pragma unroll
        for (int mt = 0; mt < 2; mt++)
          oacc[mt][dt] = __builtin_amdgcn_mfma_f32_16x16x32_bf16(pf[mt][ks], vf, oacc[mt][dt], 0, 0, 0);
      }
    }
  }

  // normalize + write O as [b][s][h*128+d] bf16
  const int b = bh >> 4, h = bh & 15;
#pragma unroll
  for (int mt = 0; mt < 2; mt++) {
    f32x4 inv;
#pragma unroll
    for (int r = 0; r < 4; r++) inv[r] = 1.0f / lrow[mt][r];
#pragma unroll
    for (int dt = 0; dt < 8; dt++) {
#pragma unroll
      for (int r = 0; r < 4; r++) {
        int q = q0 + w * 32 + mt * 16 + lb * 4 + r;
        int d = h * HDIM + dt * 16 + la;
        O[((size_t)b * SEQ + q) * D_MODEL + d] = (bf16_t)(oacc[mt][dt][r] * inv[r]);
      }
    }
  }
}

// ---------------------------------------------------------------- launch
extern "C" void kernel_launch(void* const* d_in, const int* in_sizes, int n_in,
                              void* d_out, int out_size, void* d_ws, size_t ws_size,
                              hipStream_t stream) {
  (void)in_sizes; (void)n_in; (void)out_size; (void)ws_size;
  const float* x  = (const float*)d_in[0];
  // d_in[1] = causal_mask (implicit in kernel)
  const float* Wq = (const float*)d_in[2];
  const float* bq = (const float*)d_in[3];
  const float* Wk = (const float*)d_in[4];
  const float* bk = (const float*)d_in[5];
  const float* Wv = (const float*)d_in[6];
  const float* bv = (const float*)d_in[7];
  const float* Wo = (const float*)d_in[8];
  const float* bo = (const float*)d_in[9];
  float* out = (float*)d_out;

  const size_t NBF = (size_t)MTOT * D_MODEL * sizeof(bf16_t);   // 16.8 MB
  const size_t WBF = (size_t)D_MODEL * D_MODEL * sizeof(bf16_t);// 8.4 MB
  char* p = (char*)d_ws;
  bf16_t* xb   = (bf16_t*)p; p += NBF;       // also reused for attention output O
  bf16_t* Wcat = (bf16_t*)p; p += 3 * WBF;   // [Wq|Wk|Wv] bf16
  bf16_t* Wob  = (bf16_t*)p; p += WBF;
  bf16_t* Qb   = (bf16_t*)p; p += NBF;
  bf16_t* Kb   = (bf16_t*)p; p += NBF;
  bf16_t* Vtb  = (bf16_t*)p; p += NBF;
  bf16_t* Ob   = xb;  // x dead after QKV GEMM

  const int WN4 = D_MODEL * D_MODEL / 4;   // 1048576
  const int XN4 = MTOT * D_MODEL / 4;      // 2097152
  cast_kernel<<<XN4 / 256, 256, 0, stream>>>(x, xb, XN4);
  cast_kernel<<<WN4 / 256, 256, 0, stream>>>(Wq, Wcat, WN4);
  cast_kernel<<<WN4 / 256, 256, 0, stream>>>(Wk, Wcat + (size_t)D_MODEL * D_MODEL, WN4);
  cast_kernel<<<WN4 / 256, 256, 0, stream>>>(Wv, Wcat + (size_t)2 * D_MODEL * D_MODEL, WN4);
  cast_kernel<<<WN4 / 256, 256, 0, stream>>>(Wo, Wob, WN4);

  gemm_fused<<<dim3(MTOT / 128, 6144 / 128), 256, 0, stream>>>(
      xb, Wcat, 0, bq, bk, bv, Qb, Kb, Vtb, nullptr);

  flash_attn<<<dim3(512), 256, 0, stream>>>(Qb, Kb, Vtb, Ob);

  gemm_fused<<<dim3(MTOT / 128, D_MODEL / 128), 256, 0, stream>>>(
      Ob, Wob, 1, bo, nullptr, nullptr, nullptr, nullptr, nullptr, out);
}

// Round 2
// 415.659 us; speedup vs baseline: 1.0790x; 1.0790x over previous
//
#include <hip/hip_runtime.h>
#include <hip/hip_bf16.h>
#include <stdint.h>
#include <stddef.h>

typedef __bf16 bf16_t;
typedef __bf16 bf16x4_t __attribute__((ext_vector_type(4)));
typedef __bf16 bf16x8_t __attribute__((ext_vector_type(8)));
typedef float f32x4 __attribute__((ext_vector_type(4)));

#define D_MODEL 2048
#define NHEADS 16
#define HDIM 128
#define SEQ 2048
#define BATCH 2
#define MTOT (BATCH * SEQ) /* 4096 */
#define SCALE_F 0.08838834764831845f /* 1/sqrt(128) */
#define LOG2E 1.4426950408889634f

#define AS1 __attribute__((address_space(1)))
#define AS3 __attribute__((address_space(3)))

__device__ __forceinline__ void load_lds16(const bf16_t* g, bf16_t* l) {
  __builtin_amdgcn_global_load_lds((AS1 void*)(g), (AS3 void*)(l), 16, 0, 0);
}

// ---------------------------------------------------------------- casts fp32->bf16
__global__ void cast_kernel(const float* __restrict__ src, bf16_t* __restrict__ dst, int n4) {
  int i = blockIdx.x * blockDim.x + threadIdx.x;
  if (i < n4) {
    float4 v = ((const float4*)src)[i];
    bf16x4_t o;
    o.x = (bf16_t)v.x; o.y = (bf16_t)v.y; o.z = (bf16_t)v.z; o.w = (bf16_t)v.w;
    ((bf16x4_t*)dst)[i] = o;
  }
}

// 4 weight matrices (each 2048x2048) -> one launch. y selects src; dst offset y*N.
__global__ void cast4_kernel(const float* __restrict__ s0, const float* __restrict__ s1,
                             const float* __restrict__ s2, const float* __restrict__ s3,
                             bf16_t* __restrict__ dst, int n4) {
  int i = blockIdx.x * blockDim.x + threadIdx.x;
  int y = blockIdx.y;
  if (i < n4) {
    const float* src = (y == 0) ? s0 : (y == 1) ? s1 : (y == 2) ? s2 : s3;
    float4 v = ((const float4*)src)[i];
    bf16x4_t o;
    o.x = (bf16_t)v.x; o.y = (bf16_t)v.y; o.z = (bf16_t)v.z; o.w = (bf16_t)v.w;
    ((bf16x4_t*)(dst + (size_t)y * D_MODEL * D_MODEL / 4 * 4))[i] = o;
  }
}

// ---------------------------------------------------------------- GEMM  C = A @ B^T (+bias)
// BK=64, XOR chunk-swizzled LDS: slot (row, cc) holds global chunk cc ^ (row&7).
// A: [4096][2048] bf16 row-major.  Bm: [N][2048] bf16 row-major (N x K).
// mode 0: N=6144 (q|k|v). Epilogue -> Q,K as [B,H,S,Dh]; V transposed -> [B,H,Dh,S].
// mode 1: N=2048. Epilogue -> fp32 out [4096][2048] + bias.
__global__ __launch_bounds__(256) void gemm_fused(
    const bf16_t* __restrict__ A, const bf16_t* __restrict__ Bm, int mode,
    const float* __restrict__ bias0, const float* __restrict__ bias1,
    const float* __restrict__ bias2,
    bf16_t* __restrict__ Qo, bf16_t* __restrict__ Ko, bf16_t* __restrict__ Vto,
    float* __restrict__ Out) {
  const int K = 2048;
  __shared__ __align__(16) bf16_t lA[128 * 64];
  __shared__ __align__(16) bf16_t lB[128 * 64];
  const int m0 = blockIdx.x * 128;
  const int n0 = blockIdx.y * 128;
  const int t = threadIdx.x;
  const int w = t >> 6, lane = t & 63;
  const int wm = w & 1, wn = w >> 1;
  const int la = lane & 15, lb = lane >> 4;

  f32x4 acc[4][4];
  f32x4 zero = {0.f, 0.f, 0.f, 0.f};
#pragma unroll
  for (int i = 0; i < 4; i++)
#pragma unroll
    for (int j = 0; j < 4; j++) acc[i][j] = zero;

  // staging: thread t covers (row0 + 32*i, chunk cc), stores global chunk cc^(row&7).
  // (row+32)&7 == row&7, so the swizzled chunk index is i-invariant.
  const int row0 = t >> 3, cc = t & 7;
  const int ccs = cc ^ (row0 & 7);
  const bf16_t* gA = A + (size_t)(m0 + row0) * K + ccs * 8;
  const bf16_t* gB = Bm + (size_t)(n0 + row0) * K + ccs * 8;
  bf16_t* sA = lA + t * 8;
  bf16_t* sB = lB + t * 8;

  for (int k0 = 0; k0 < K; k0 += 64) {
    __syncthreads();
#pragma unroll
    for (int i = 0; i < 4; i++)
      load_lds16(gA + k0 + (size_t)(32 * i) * K, sA + 2048 * i);
#pragma unroll
    for (int i = 0; i < 4; i++)
      load_lds16(gB + k0 + (size_t)(32 * i) * K, sB + 2048 * i);
    __syncthreads();
#pragma unroll
    for (int ks = 0; ks < 2; ks++) {
      bf16x8_t af[4], bfr[4];
#pragma unroll
      for (int mt = 0; mt < 4; mt++) {
        int row = wm * 64 + mt * 16 + la;
        af[mt] = *(const bf16x8_t*)(lA + row * 64 + (((ks * 4 + lb) ^ (la & 7)) * 8));
      }
#pragma unroll
      for (int nt = 0; nt < 4; nt++) {
        int row = wn * 64 + nt * 16 + la;
        bfr[nt] = *(const bf16x8_t*)(lB + row * 64 + (((ks * 4 + lb) ^ (la & 7)) * 8));
      }
#pragma unroll
      for (int mt = 0; mt < 4; mt++)
#pragma unroll
        for (int nt = 0; nt < 4; nt++)
          acc[mt][nt] = __builtin_amdgcn_mfma_f32_16x16x32_bf16(af[mt], bfr[nt], acc[mt][nt], 0, 0, 0);
    }
  }

  if (mode == 0) {
#pragma unroll
    for (int mt = 0; mt < 4; mt++) {
#pragma unroll
      for (int nt = 0; nt < 4; nt++) {
        int m = m0 + wm * 64 + mt * 16 + lb * 4; // rows m..m+3
        int n = n0 + wn * 64 + nt * 16 + la;
        int b = m >> 11, s = m & 2047;
        int which = n >> 11, hd = n & 2047;
        int h = hd >> 7, d = hd & 127;
        float bv = (which == 0 ? bias0 : which == 1 ? bias1 : bias2)[hd];
        f32x4 v = acc[mt][nt];
        if (which == 2) {
          bf16_t* dst = Vto + ((size_t)(b * NHEADS + h) * HDIM + d) * SEQ + s;
          bf16x4_t pk;
          pk.x = (bf16_t)(v.x + bv); pk.y = (bf16_t)(v.y + bv);
          pk.z = (bf16_t)(v.z + bv); pk.w = (bf16_t)(v.w + bv);
          *(bf16x4_t*)dst = pk;
        } else {
          bf16_t* dst = (which == 0 ? Qo : Ko) + ((size_t)(b * NHEADS + h) * SEQ + s) * HDIM + d;
          dst[0]        = (bf16_t)(v.x + bv);
          dst[HDIM]     = (bf16_t)(v.y + bv);
          dst[2 * HDIM] = (bf16_t)(v.z + bv);
          dst[3 * HDIM] = (bf16_t)(v.w + bv);
        }
      }
    }
  } else {
#pragma unroll
    for (int mt = 0; mt < 4; mt++) {
#pragma unroll
      for (int nt = 0; nt < 4; nt++) {
        int m = m0 + wm * 64 + mt * 16 + lb * 4;
        int n = n0 + wn * 64 + nt * 16 + la;
        float bv = bias0[n];
        f32x4 v = acc[mt][nt];
        float* dst = Out + (size_t)m * D_MODEL + n;
        dst[0]           = v.x + bv;
        dst[D_MODEL]     = v.y + bv;
        dst[2 * D_MODEL] = v.z + bv;
        dst[3 * D_MODEL] = v.w + bv;
      }
    }
  }
}

// ---------------------------------------------------------------- causal flash attention
// Q,K: [32][2048][128] bf16.  Vt: [32][128][2048] bf16.  O: [2][2048][2048] bf16.
// Softmax carried in log2 domain (exp2 native).
__global__ __launch_bounds__(256) void flash_attn(
    const bf16_t* __restrict__ Q, const bf16_t* __restrict__ Kg,
    const bf16_t* __restrict__ Vt, bf16_t* __restrict__ O) {
  __shared__ __align__(16) bf16_t lK[64 * 128];  // [j][d], chunk-swizzled
  __shared__ __align__(16) bf16_t lV[128 * 64];  // [d][j], chunk-swizzled
  __shared__ __align__(16) bf16_t lP[128 * 72];  // [q][j], padded stride 72
  int g = blockIdx.x;
  int qt, bh;
  if (g < 256) { qt = g >> 5; bh = g & 31; }
  else         { qt = 15 - ((g - 256) >> 5); bh = g & 31; }
  const int q0 = qt * 128;
  const int t = threadIdx.x;
  const int w = t >> 6, lane = t & 63;
  const int la = lane & 15, lb = lane >> 4;

  const bf16_t* Qb = Q + (size_t)bh * SEQ * HDIM;
  const bf16_t* Kb = Kg + (size_t)bh * SEQ * HDIM;
  const bf16_t* Vb = Vt + (size_t)bh * HDIM * SEQ;

  // Q fragments in registers: rows q0+32w+16mt+la, k = 32ks + 8lb + i
  bf16x8_t qf[2][4];
#pragma unroll
  for (int mt = 0; mt < 2; mt++)
#pragma unroll
    for (int ks = 0; ks < 4; ks++)
      qf[mt][ks] = *(const bf16x8_t*)(Qb + (size_t)(q0 + w * 32 + mt * 16 + la) * HDIM + ks * 32 + lb * 8);

  f32x4 oacc[2][8];
  float mrow[2][4], lrow[2][4];
  f32x4 zero = {0.f, 0.f, 0.f, 0.f};
#pragma unroll
  for (int mt = 0; mt < 2; mt++) {
#pragma unroll
    for (int dt = 0; dt < 8; dt++) oacc[mt][dt] = zero;
#pragma unroll
    for (int r = 0; r < 4; r++) { mrow[mt][r] = -3.0e38f; lrow[mt][r] = 0.f; }
  }

  const float scale2 = SCALE_F * LOG2E;
  const int nkt = qt * 2 + 2;
  for (int kt = 0; kt < nkt; kt++) {
    const int j0 = kt * 64;
    __syncthreads();
    // stage K-tile [64][128]: chunk (j, cc') holds global chunk (j, cc'^ (j&15))
#pragma unroll
    for (int i = 0; i < 4; i++) {
      int slot = t + 256 * i;
      int j = slot >> 4, cc = slot & 15;
      load_lds16(Kb + (size_t)(j0 + j) * HDIM + ((cc ^ (j & 15)) * 8), lK + slot * 8);
    }
    // stage Vt-tile [128][64]: chunk (d, jc') holds global chunk (d, jc'^(d&7))
#pragma unroll
    for (int i = 0; i < 4; i++) {
      int slot = t + 256 * i;
      int d = slot >> 3, jc = slot & 7;
      load_lds16(Vb + (size_t)d * SEQ + j0 + ((jc ^ (d & 7)) * 8), lV + slot * 8);
    }
    __syncthreads();

    // S = Q @ K^T   (rows: this wave's 32 q's; cols: 64 j's)
    f32x4 sacc[2][4];
#pragma unroll
    for (int mt = 0; mt < 2; mt++)
#pragma unroll
      for (int nt = 0; nt < 4; nt++) sacc[mt][nt] = zero;
#pragma unroll
    for (int ks = 0; ks < 4; ks++) {
#pragma unroll
      for (int nt = 0; nt < 4; nt++) {
        int j = nt * 16 + la;
        int cc = (lb + 4 * ks) ^ (j & 15);
        bf16x8_t kf = *(const bf16x8_t*)(lK + j * 128 + cc * 8);
#pragma unroll
        for (int mt = 0; mt < 2; mt++)
          sacc[mt][nt] = __builtin_amdgcn_mfma_f32_16x16x32_bf16(qf[mt][ks], kf, sacc[mt][nt], 0, 0, 0);
      }
    }

    // scale (log2 domain) + causal mask + online softmax
#pragma unroll
    for (int mt = 0; mt < 2; mt++) {
      int qrow = q0 + w * 32 + mt * 16 + lb * 4;
      f32x4 rmax;
#pragma unroll
      for (int r = 0; r < 4; r++) {
        float x = -3.0e38f;
#pragma unroll
        for (int nt = 0; nt < 4; nt++) {
          int j = j0 + nt * 16 + la;
          float sv = sacc[mt][nt][r] * scale2;
          if (j > qrow + r) sv = -3.0e38f;
          sacc[mt][nt][r] = sv;
          x = fmaxf(x, sv);
        }
        rmax[r] = x;
      }
#pragma unroll
      for (int off = 1; off < 16; off <<= 1)
#pragma unroll
        for (int r = 0; r < 4; r++) rmax[r] = fmaxf(rmax[r], __shfl_xor(rmax[r], off));
      f32x4 rsum;
#pragma unroll
      for (int r = 0; r < 4; r++) {
        float mnew = fmaxf(mrow[mt][r], rmax[r]);
        float alpha = exp2f(mrow[mt][r] - mnew);
        mrow[mt][r] = mnew;
        lrow[mt][r] *= alpha;
#pragma unroll
        for (int dt = 0; dt < 8; dt++) oacc[mt][dt][r] *= alpha;
        float s = 0.f;
#pragma unroll
        for (int nt = 0; nt < 4; nt++) {
          float pex = exp2f(sacc[mt][nt][r] - mnew);
          sacc[mt][nt][r] = pex;
          s += pex;
        }
        rsum[r] = s;
      }
#pragma unroll
      for (int off = 1; off < 16; off <<= 1)
#pragma unroll
        for (int r = 0; r < 4; r++) rsum[r] += __shfl_xor(rsum[r], off);
#pragma unroll
      for (int r = 0; r < 4; r++) lrow[mt][r] += rsum[r];
      // write P (this wave's own 32 rows only -> no cross-wave barrier needed)
#pragma unroll
      for (int nt = 0; nt < 4; nt++)
#pragma unroll
        for (int r = 0; r < 4; r++)
          lP[(w * 32 + mt * 16 + lb * 4 + r) * 72 + nt * 16 + la] = (bf16_t)sacc[mt][nt][r];
    }

    // O += P @ V
    bf16x8_t pf[2][2];
#pragma unroll
    for (int mt = 0; mt < 2; mt++)
#pragma unroll
      for (int ks = 0; ks < 2; ks++)
        pf[mt][ks] = *(const bf16x8_t*)(lP + (w * 32 + mt * 16 + la) * 72 + ks * 32 + lb * 8);
#pragma unroll
    for (int ks = 0; ks < 2; ks++) {
#pragma unroll
      for (int dt = 0; dt < 8; dt++) {
        int d = dt * 16 + la;
        int jc = (lb + 4 * ks) ^ (d & 7);
        bf16x8_t vf = *(const bf16x8_t*)(lV + d * 64 + jc * 8);
#pragma unroll
        for (int mt = 0; mt < 2; mt++)
          oacc[mt][dt] = __builtin_amdgcn_mfma_f32_16x16x32_bf16(pf[mt][ks], vf, oacc[mt][dt], 0, 0, 0);
      }
    }
  }

  // normalize + write O as [b][s][h*128+d] bf16
  const int b = bh >> 4, h = bh & 15;
#pragma unroll
  for (int mt = 0; mt < 2; mt++) {
    f32x4 inv;
#pragma unroll
    for (int r = 0; r < 4; r++) inv[r] = 1.0f / lrow[mt][r];
#pragma unroll
    for (int dt = 0; dt < 8; dt++) {
#pragma unroll
      for (int r = 0; r < 4; r++) {
        int q = q0 + w * 32 + mt * 16 + lb * 4 + r;
        int d = h * HDIM + dt * 16 + la;
        O[((size_t)b * SEQ + q) * D_MODEL + d] = (bf16_t)(oacc[mt][dt][r] * inv[r]);
      }
    }
  }
}

// ---------------------------------------------------------------- launch
extern "C" void kernel_launch(void* const* d_in, const int* in_sizes, int n_in,
                              void* d_out, int out_size, void* d_ws, size_t ws_size,
                              hipStream_t stream) {
  (void)in_sizes; (void)n_in; (void)out_size; (void)ws_size;
  const float* x  = (const float*)d_in[0];
  // d_in[1] = causal_mask (implicit in kernel)
  const float* Wq = (const float*)d_in[2];
  const float* bq = (const float*)d_in[3];
  const float* Wk = (const float*)d_in[4];
  const float* bk = (const float*)d_in[5];
  const float* Wv = (const float*)d_in[6];
  const float* bv = (const float*)d_in[7];
  const float* Wo = (const float*)d_in[8];
  const float* bo = (const float*)d_in[9];
  float* out = (float*)d_out;

  const size_t NBF = (size_t)MTOT * D_MODEL * sizeof(bf16_t);   // 16.8 MB
  const size_t WBF = (size_t)D_MODEL * D_MODEL * sizeof(bf16_t);// 8.4 MB
  char* p = (char*)d_ws;
  bf16_t* xb   = (bf16_t*)p; p += NBF;       // also reused for attention output O
  bf16_t* Wcat = (bf16_t*)p; p += 4 * WBF;   // [Wq|Wk|Wv|Wo] bf16
  bf16_t* Qb   = (bf16_t*)p; p += NBF;
  bf16_t* Kb   = (bf16_t*)p; p += NBF;
  bf16_t* Vtb  = (bf16_t*)p; p += NBF;
  bf16_t* Wob  = Wcat + (size_t)3 * D_MODEL * D_MODEL;
  bf16_t* Ob   = xb;  // x dead after QKV GEMM

  const int WN4 = D_MODEL * D_MODEL / 4;   // 1048576
  const int XN4 = MTOT * D_MODEL / 4;      // 2097152
  cast_kernel<<<XN4 / 256, 256, 0, stream>>>(x, xb, XN4);
  cast4_kernel<<<dim3(WN4 / 256, 4), 256, 0, stream>>>(Wq, Wk, Wv, Wo, Wcat, WN4);

  gemm_fused<<<dim3(MTOT / 128, 6144 / 128), 256, 0, stream>>>(
      xb, Wcat, 0, bq, bk, bv, Qb, Kb, Vtb, nullptr);

  flash_attn<<<dim3(512), 256, 0, stream>>>(Qb, Kb, Vtb, Ob);

  gemm_fused<<<dim3(MTOT / 128, D_MODEL / 128), 256, 0, stream>>>(
      Ob, Wob, 1, bo, nullptr, nullptr, nullptr, nullptr, nullptr, out);
}